// Round 9
// baseline (15119.527 us; speedup 1.0000x reference)
//
#include <hip/hip_runtime.h>
#include <hip/hip_bf16.h>
#include <cstdint>
#include <cstddef>

namespace {

constexpr int S_LEN  = 256;
constexpr int BATCH  = 256;
constexpr int NH     = 512;
constexpr int NE     = 256;
constexpr int NSTEPS = 127;          // TGT_LEN-1
constexpr int N1     = 2048;         // [Wo;Wz;Wr;Wn_partial]
constexpr size_t SB        = (size_t)S_LEN * BATCH;   // 65536
constexpr size_t SRC_ELEMS = SB * NH;                 // 33,554,432

typedef __attribute__((ext_vector_type(8))) short  short8v;
typedef __attribute__((ext_vector_type(4))) float  float4v;
typedef unsigned short us;

constexpr int EPI_EPROJ = 1, EPI_S0 = 4;

__device__ __forceinline__ float bf2f(us u) {
  union { unsigned int i; float f; } c; c.i = ((unsigned int)u) << 16; return c.f;
}
__device__ __forceinline__ us f2bf(float f) {
  union { float f; unsigned int i; } c; c.f = f;
  unsigned int x = c.i;
  return (us)((x + 0x7FFFu + ((x >> 16) & 1u)) >> 16);
}
// tanh(x) = 1 - 2/(e^{2x}+1)
__device__ __forceinline__ float tanh2(float x) {
  return 1.f - 2.f * __builtin_amdgcn_rcpf(__expf(2.f * x) + 1.f);
}
__device__ __forceinline__ float sigm(float x) {
  return __builtin_amdgcn_rcpf(1.f + __expf(-x));
}
// one wave stages 1KB: per-lane global addr g (lane*16B apart), uniform LDS dst l
__device__ __forceinline__ void gload16(const us* g, us* l) {
  __builtin_amdgcn_global_load_lds(
      (const __attribute__((address_space(1))) unsigned int*)g,
      (__attribute__((address_space(3))) unsigned int*)l, 16, 0, 0);
}

// ---------------- prologue: conversions ----------------

// src_enc (S,B,H) f32 -> src_t (B,S,H) bf16
__global__ void k_conv_src(const float* __restrict__ src, us* __restrict__ dst) {
  const int total = S_LEN * BATCH * 64;       // 8-elem chunks, dest-linear
  int i = blockIdx.x * blockDim.x + threadIdx.x;
  int stride = gridDim.x * blockDim.x;
  for (; i < total; i += stride) {
    int c = i & 63, s = (i >> 6) & 255, b = i >> 14;
    const float* p = src + ((size_t)s * BATCH + b) * NH + c * 8;
    float4 v0 = *(const float4*)p;
    float4 v1 = *(const float4*)(p + 4);
    us o[8] = { f2bf(v0.x), f2bf(v0.y), f2bf(v0.z), f2bf(v0.w),
                f2bf(v1.x), f2bf(v1.y), f2bf(v1.z), f2bf(v1.w) };
    *(short8v*)(dst + (size_t)i * 8) = *(const short8v*)o;
  }
}

__global__ void k_conv_w(const float* __restrict__ Wo, const float* __restrict__ Wz,
                         const float* __restrict__ Wr, const float* __restrict__ Wn,
                         const float* __restrict__ Wa, const float* __restrict__ Ws,
                         const float* __restrict__ Wob, const float* __restrict__ Wzb,
                         const float* __restrict__ Wrb, const float* __restrict__ Wnb,
                         us* __restrict__ W1cat, us* __restrict__ Wns,
                         us* __restrict__ Was, us* __restrict__ Wae,
                         us* __restrict__ Wsbf, float* __restrict__ bcat) {
  const int T1 = 2048 * 1280;
  const int T2 = 512 * 512;
  const int total = T1 + 4 * T2 + 2048;
  int i = blockIdx.x * blockDim.x + threadIdx.x;
  int stride = gridDim.x * blockDim.x;
  for (; i < total; i += stride) {
    int idx = i;
    if (idx < T1) {
      int row = idx / 1280, col = idx - row * 1280;
      float v;
      if      (row < 512)  v = Wo[row * 1280 + col];
      else if (row < 1024) v = Wz[(row - 512) * 1280 + col];
      else if (row < 1536) v = Wr[(row - 1024) * 1280 + col];
      else {
        int g = row - 1536;
        v = (col >= 256 && col < 768) ? 0.f : Wn[g * 1280 + col];
      }
      W1cat[idx] = f2bf(v);
    } else if ((idx -= T1) < T2) {
      int g = idx >> 9, j = idx & 511;
      Wns[idx] = f2bf(Wn[g * 1280 + 256 + j]);
    } else if ((idx -= T2) < T2) {
      int g = idx >> 9, h = idx & 511;
      Was[idx] = f2bf(Wa[g * 1024 + h]);
    } else if ((idx -= T2) < T2) {
      int g = idx >> 9, h = idx & 511;
      Wae[idx] = f2bf(Wa[g * 1024 + 512 + h]);
    } else if ((idx -= T2) < T2) {
      Wsbf[idx] = f2bf(Ws[idx]);
    } else {
      idx -= T2;
      bcat[idx] = (idx < 512) ? Wob[idx]
                : (idx < 1024) ? Wzb[idx - 512]
                : (idx < 1536) ? Wrb[idx - 1024]
                               : Wnb[idx - 1536];
    }
  }
}

__global__ void k_emb(const int* __restrict__ tgt, const float* __restrict__ table,
                      us* __restrict__ emb) {
  const int total = NSTEPS * BATCH * NE;
  int i = blockIdx.x * blockDim.x + threadIdx.x;
  int stride = gridDim.x * blockDim.x;
  for (; i < total; i += stride) {
    int e  = i & (NE - 1);
    int tb = i >> 8;
    int sym = tgt[tb];
    emb[i] = f2bf(table[sym * NE + e]);
  }
}

// ------------- prologue 8-wave MFMA GEMM tile: 64x128, BK=64 (s0 / eproj) ----------
template<int EPI>
__global__ __launch_bounds__(512, 2) void k_gemm(
    const us* __restrict__ A0, int lda, const us* __restrict__ Bw, int ldb, int K,
    const float* __restrict__ bias, float* __restrict__ f0, us* __restrict__ g0) {
  __shared__ alignas(16) char smem[49152];
  char* As0 = smem;               // 2 x 8192
  char* Bs0 = smem + 16384;       // 2 x 16384
  const int tid = threadIdx.x;
  const int m0 = blockIdx.x * 64, n0 = blockIdx.y * 128;
  const int arow = tid >> 3, ac = (tid & 7) * 8;
  const int brow = tid >> 2, bc = (tid & 3) * 16;
  short8v ar, br0, br1;

  auto loadT = [&](int k0) {
    ar = *(const short8v*)(A0 + (size_t)(m0 + arow) * lda + (k0 + ac));
    const us* q = Bw + (size_t)(n0 + brow) * ldb + (k0 + bc);
    br0 = *(const short8v*)q;
    br1 = *(const short8v*)(q + 8);
  };
  auto stage = [&](int buf) {
    *(short8v*)(As0 + buf * 8192 + arow * 128 + ((ac * 2) ^ ((arow & 7) << 4))) = ar;
    char* bb = Bs0 + buf * 16384 + brow * 128;
    const int sw = (brow & 7) << 4;
    *(short8v*)(bb + ((bc * 2) ^ sw)) = br0;
    *(short8v*)(bb + ((bc * 2 + 16) ^ sw)) = br1;
  };

  const int lane = tid & 63, wave = tid >> 6;
  const int wm = (wave >> 2) * 32, wn = (wave & 3) * 32;
  const int fr = lane & 15, kq = lane >> 4;
  const int ra0 = wm + fr, ra1 = ra0 + 16;
  const int rb0 = wn + fr, rb1 = rb0 + 16;
  float4v acc00 = {0,0,0,0}, acc01 = {0,0,0,0}, acc10 = {0,0,0,0}, acc11 = {0,0,0,0};

  loadT(0);
  stage(0);
  const int nit = K >> 6;
  for (int it = 0; it < nit; ++it) {
    __syncthreads();
    if (it + 1 < nit) loadT((it + 1) << 6);
    const char* ab = As0 + (it & 1) * 8192;
    const char* bb = Bs0 + (it & 1) * 16384;
    #pragma unroll
    for (int ks = 0; ks < 2; ++ks) {
      const int cb = ks * 64 + kq * 16;
      short8v a0 = *(const short8v*)(ab + ra0 * 128 + (cb ^ ((ra0 & 7) << 4)));
      short8v a1 = *(const short8v*)(ab + ra1 * 128 + (cb ^ ((ra1 & 7) << 4)));
      short8v b0 = *(const short8v*)(bb + rb0 * 128 + (cb ^ ((rb0 & 7) << 4)));
      short8v b1 = *(const short8v*)(bb + rb1 * 128 + (cb ^ ((rb1 & 7) << 4)));
      acc00 = __builtin_amdgcn_mfma_f32_16x16x32_bf16(a0, b0, acc00, 0, 0, 0);
      acc01 = __builtin_amdgcn_mfma_f32_16x16x32_bf16(a0, b1, acc01, 0, 0, 0);
      acc10 = __builtin_amdgcn_mfma_f32_16x16x32_bf16(a1, b0, acc10, 0, 0, 0);
      acc11 = __builtin_amdgcn_mfma_f32_16x16x32_bf16(a1, b1, acc11, 0, 0, 0);
    }
    if (it + 1 < nit) stage((it + 1) & 1);
  }

  #pragma unroll
  for (int am = 0; am < 2; ++am) {
    #pragma unroll
    for (int bn = 0; bn < 2; ++bn) {
      float4v a = am ? (bn ? acc11 : acc10) : (bn ? acc01 : acc00);
      #pragma unroll
      for (int r = 0; r < 4; ++r) {
        const int rowO = m0 + wm + am * 16 + kq * 4 + r;
        const int colO = n0 + wn + bn * 16 + fr;
        float v = a[r];
        if (EPI == EPI_S0) {
          float tv = tanh2(v + bias[colO]);
          f0[(size_t)rowO * 512 + colO] = tv;
          g0[(size_t)rowO * 512 + colO] = f2bf(tv);
        } else { // EPI_EPROJ
          g0[(size_t)rowO * 512 + colO] = f2bf(v + bias[colO]);
        }
      }
    }
  }
}

// ---- k_stepA: GRU-finish + q (wave-per-row coalesced matvecs) + scores + ci ----
__global__ __launch_bounds__(512, 1) void k_stepA(
    const us* __restrict__ ep,        // (B,S,H) bf16
    const us* __restrict__ src,       // (B,S,H) bf16
    const us* __restrict__ Wns, const us* __restrict__ Was,
    const float* __restrict__ vaw, const int* __restrict__ slen,
    const float* __restrict__ zi, const float* __restrict__ npart,
    const us* __restrict__ xn,
    float* __restrict__ s_f32, us* __restrict__ s_bf, us* __restrict__ ci_bf,
    float* __restrict__ dec_st_t, float* __restrict__ dec_at_t, int has_gru) {
  __shared__ alignas(16) us stg[3][32][512];   // 96KB, 3-deep stream buffers
  __shared__ float sfl[512];
  __shared__ float q2l[512];
  __shared__ float nacc[512];
  __shared__ float pl[256];
  __shared__ float lred[8];
  __shared__ float wpart[8][512];              // 16KB
  const int b = blockIdx.x, tid = threadIdx.x;
  const int lane = tid & 63, wv = tid >> 6;    // 8 waves
  const int g0l = lane * 8;
  const int len = slen[b];
  const us* epb  = ep  + (size_t)b * S_LEN * NH;
  const us* srcb = src + (size_t)b * S_LEN * NH;

  // hoisted attention constants
  float vv2[8]; float sumv = 0.f;
  {
    const float* vp = vaw + g0l;
    #pragma unroll
    for (int j = 0; j < 8; j++) { vv2[j] = 2.f * vp[j]; sumv += vp[j]; }
    #pragma unroll
    for (int off = 32; off > 0; off >>= 1) sumv += __shfl_xor(sumv, off, 64);
  }

  // ---- M1: GRU finish of step t-1 -> s_t (wave-per-row matvec vs Wns) ----
  float s_new;
  if (has_gru) {
    // lane-local xn slice (elems g0l..g0l+7) in registers
    float xv[8];
    {
      short8v xr = *(const short8v*)(xn + b * 512 + g0l);
      #pragma unroll
      for (int j = 0; j < 8; j++) xv[j] = bf2f((us)xr[j]);
    }
    const us* wr0 = Wns + (size_t)(wv * 64) * 512 + g0l;
    #pragma unroll 4
    for (int r = 0; r < 64; ++r) {
      short8v w8 = *(const short8v*)(wr0 + (size_t)r * 512);
      float acc = 0.f;
      #pragma unroll
      for (int j = 0; j < 8; j++)
        acc = __builtin_fmaf(bf2f((us)w8[j]), xv[j], acc);
      #pragma unroll
      for (int off = 32; off > 0; off >>= 1) acc += __shfl_xor(acc, off, 64);
      if (lane == 0) nacc[wv * 64 + r] = acc;
    }
    __syncthreads();
    float nv = tanh2(npart[b * 512 + tid] + nacc[tid]);
    float z  = zi[b * 512 + tid];
    float so = s_f32[b * 512 + tid];
    s_new = (1.f - z) * so + z * nv;
    s_f32[b * 512 + tid] = s_new;
    s_bf[b * 512 + tid]  = f2bf(s_new);
  } else {
    s_new = s_f32[b * 512 + tid];
  }
  sfl[tid] = s_new;
  __builtin_nontemporal_store(s_new, &dec_st_t[b * 512 + tid]);
  __syncthreads();

  // ---- M2: q = 2 * (s_t @ Was^T) (wave-per-row matvec) ----
  {
    float sv[8];
    #pragma unroll
    for (int j = 0; j < 8; j++) sv[j] = sfl[g0l + j];
    const us* wr0 = Was + (size_t)(wv * 64) * 512 + g0l;
    #pragma unroll 4
    for (int r = 0; r < 64; ++r) {
      short8v w8 = *(const short8v*)(wr0 + (size_t)r * 512);
      float acc = 0.f;
      #pragma unroll
      for (int j = 0; j < 8; j++)
        acc = __builtin_fmaf(bf2f((us)w8[j]), sv[j], acc);
      #pragma unroll
      for (int off = 32; off > 0; off >>= 1) acc += __shfl_xor(acc, off, 64);
      if (lane == 0) q2l[wv * 64 + r] = 2.f * acc;
    }
  }
  __syncthreads();

  // ---- D: scores + exp (max-free: |ei| <= sum|va| ~ 20, f32-safe) ----
  // stream prefetch issued only now (after all other global ops) so the
  // counted vmcnt FIFO logic is safe: newest 8/4 outstanding = our loads.
  auto issue = [&](const us* base, int chunk, int buf) {
    #pragma unroll
    for (int i = 0; i < 4; ++i) {
      int r = wv * 4 + i;
      gload16(base + (size_t)(chunk * 32 + r) * NH + g0l, &stg[buf][r][0]);
    }
  };
  issue(epb, 0, 0); issue(epb, 1, 1); issue(epb, 2, 2);
  float q2[8];
  #pragma unroll
  for (int j = 0; j < 8; j++) q2[j] = q2l[g0l + j];
  float lsum = 0.f;
  #pragma unroll
  for (int c = 0; c < 8; ++c) {
    if (c < 6)       asm volatile("s_waitcnt vmcnt(8)" ::: "memory");
    else if (c == 6) asm volatile("s_waitcnt vmcnt(4)" ::: "memory");
    else             asm volatile("s_waitcnt vmcnt(0)" ::: "memory");
    #pragma unroll
    for (int i = 0; i < 4; ++i) {
      const int r = wv * 4 + i;
      const int s = c * 32 + r;
      short8v v = *(const short8v*)&stg[c % 3][r][g0l];
      float acc = 0.f;
      #pragma unroll
      for (int j = 0; j < 8; j++) {
        float arg = __builtin_fmaf(bf2f((us)v[j]), 2.f, q2[j]);
        acc = __builtin_fmaf(vv2[j], __builtin_amdgcn_rcpf(__expf(arg) + 1.f), acc);
      }
      #pragma unroll
      for (int off = 32; off > 0; off >>= 1) acc += __shfl_xor(acc, off, 64);
      float p = (s < len) ? __expf(sumv - acc) : 0.f;
      if (lane == 0) pl[s] = p;
      lsum += p;
    }
    // ensure ds_reads of this buffer completed before refilling it
    asm volatile("s_waitcnt lgkmcnt(0)" ::: "memory");
    __builtin_amdgcn_sched_barrier(0);
    if (c + 3 < 8) issue(epb, c + 3, (c + 3) % 3);
  }
  if (lane == 0) lred[wv] = lsum;
  __syncthreads();
  float l = 0.f;
  #pragma unroll
  for (int w = 0; w < 8; w++) l += lred[w];
  const float inv = __builtin_amdgcn_rcpf(l);

  // ---- E: attention weights out; prefetch src ----
  if (tid < 256)
    __builtin_nontemporal_store(pl[tid] * inv, &dec_at_t[b * 256 + tid]);
  issue(srcb, 0, 0); issue(srcb, 1, 1); issue(srcb, 2, 2);

  // ---- F: ci = (sum_s p[s]*src[b,s,:]) * inv ----
  float a8[8] = {0,0,0,0,0,0,0,0};
  #pragma unroll
  for (int c = 0; c < 8; ++c) {
    if (c < 6)       asm volatile("s_waitcnt vmcnt(8)" ::: "memory");
    else if (c == 6) asm volatile("s_waitcnt vmcnt(4)" ::: "memory");
    else             asm volatile("s_waitcnt vmcnt(0)" ::: "memory");
    #pragma unroll
    for (int i = 0; i < 4; ++i) {
      const int r = wv * 4 + i;
      const int s = c * 32 + r;
      short8v v = *(const short8v*)&stg[c % 3][r][g0l];
      float pv = pl[s];
      #pragma unroll
      for (int j = 0; j < 8; j++)
        a8[j] = __builtin_fmaf(pv, bf2f((us)v[j]), a8[j]);
    }
    asm volatile("s_waitcnt lgkmcnt(0)" ::: "memory");
    __builtin_amdgcn_sched_barrier(0);
    if (c + 3 < 8) issue(srcb, c + 3, (c + 3) % 3);
  }
  #pragma unroll
  for (int j = 0; j < 8; j++) wpart[wv][g0l + j] = a8[j];
  __syncthreads();
  float cv = 0.f;
  #pragma unroll
  for (int w = 0; w < 8; w++) cv += wpart[w][tid];
  ci_bf[b * 512 + tid] = f2bf(cv * inv);
}

// -------- k_stepB: Y = [emb|s|ci] @ W1cat^T + bcat --------
__global__ __launch_bounds__(256, 4) void k_stepB(
    const us* __restrict__ emb_t, const us* __restrict__ sbf,
    const us* __restrict__ cibf, const us* __restrict__ W1cat,
    const float* __restrict__ bcat, const float* __restrict__ s_f32,
    float* __restrict__ dec_out_t, float* __restrict__ zi,
    float* __restrict__ npart, us* __restrict__ xn) {
  __shared__ alignas(16) char smem[24576];
  const int bid = blockIdx.x, tid = threadIdx.x;
  const int lane = tid & 63, wv = tid >> 6;
  char* As = smem;            // 64 x 128B
  char* Bs = smem + 8192;     // 128 x 128B
  const int m0 = (bid >> 4) * 64, n0 = (bid & 15) * 128;
  const int fr = lane & 15, kq = lane >> 4;
  const int wm = (wv & 1) * 32, wn0 = (wv >> 1) * 32;
  const int ra0 = wm + fr, ra1 = ra0 + 16;
  float4v acc[2][2][2];
  #pragma unroll
  for (int x = 0; x < 2; x++)
    #pragma unroll
    for (int y = 0; y < 2; y++)
      #pragma unroll
      for (int z = 0; z < 2; z++) acc[x][y][z] = (float4v){0,0,0,0};

  for (int kt = 0; kt < 20; ++kt) {
    __syncthreads();
    #pragma unroll
    for (int j = 0; j < 2; j++) {
      int cid = tid + 256 * j;
      int arow = cid >> 3, ac8 = (cid & 7) * 8;
      int cc = kt * 64 + ac8, rowg = m0 + arow;
      const us* p = (cc < 256) ? emb_t + (size_t)rowg * 256 + cc
                  : (cc < 768) ? sbf + (size_t)rowg * 512 + (cc - 256)
                               : cibf + (size_t)rowg * 512 + (cc - 768);
      *(short8v*)(As + arow * 128 + ((ac8 * 2) ^ ((arow & 7) << 4))) =
          *(const short8v*)p;
    }
    #pragma unroll
    for (int j = 0; j < 4; j++) {
      int cid = tid + 256 * j;
      int brow = cid >> 3, bc8 = (cid & 7) * 8;
      *(short8v*)(Bs + brow * 128 + ((bc8 * 2) ^ ((brow & 7) << 4))) =
          *(const short8v*)(W1cat + (size_t)(n0 + brow) * 1280 + kt * 64 + bc8);
    }
    __syncthreads();
    #pragma unroll
    for (int ks = 0; ks < 2; ++ks) {
      const int cb = ks * 64 + kq * 16;
      short8v a0 = *(const short8v*)(As + ra0 * 128 + (cb ^ ((ra0 & 7) << 4)));
      short8v a1 = *(const short8v*)(As + ra1 * 128 + (cb ^ ((ra1 & 7) << 4)));
      #pragma unroll
      for (int nh = 0; nh < 2; ++nh) {
        const int rb0 = wn0 + nh * 64 + fr, rb1 = rb0 + 16;
        short8v b0 = *(const short8v*)(Bs + rb0 * 128 + (cb ^ ((rb0 & 7) << 4)));
        short8v b1 = *(const short8v*)(Bs + rb1 * 128 + (cb ^ ((rb1 & 7) << 4)));
        acc[nh][0][0] = __builtin_amdgcn_mfma_f32_16x16x32_bf16(a0, b0, acc[nh][0][0], 0, 0, 0);
        acc[nh][0][1] = __builtin_amdgcn_mfma_f32_16x16x32_bf16(a0, b1, acc[nh][0][1], 0, 0, 0);
        acc[nh][1][0] = __builtin_amdgcn_mfma_f32_16x16x32_bf16(a1, b0, acc[nh][1][0], 0, 0, 0);
        acc[nh][1][1] = __builtin_amdgcn_mfma_f32_16x16x32_bf16(a1, b1, acc[nh][1][1], 0, 0, 0);
      }
    }
  }

  #pragma unroll
  for (int nh = 0; nh < 2; ++nh) {
    #pragma unroll
    for (int am = 0; am < 2; ++am) {
      #pragma unroll
      for (int bn = 0; bn < 2; ++bn) {
        #pragma unroll
        for (int r = 0; r < 4; ++r) {
          const int rowO = m0 + wm + am * 16 + kq * 4 + r;
          const int colO = n0 + wn0 + nh * 64 + bn * 16 + fr;
          float v = acc[nh][am][bn][r] + bcat[colO];
          const int qd = colO >> 9, j = colO & 511;
          const size_t idx = (size_t)rowO * 512 + j;
          if      (qd == 0) __builtin_nontemporal_store(v, &dec_out_t[idx]);
          else if (qd == 1) zi[idx] = sigm(v);
          else if (qd == 2) xn[idx] = f2bf(sigm(v) * s_f32[idx]);
          else              npart[idx] = v;
        }
      }
    }
  }
}

} // namespace

extern "C" void kernel_launch(void* const* d_in, const int* in_sizes, int n_in,
                              void* d_out, int out_size, void* d_ws, size_t ws_size,
                              hipStream_t stream) {
  const float* src_enc  = (const float*)d_in[0];
  const int*   tgt      = (const int*)d_in[1];
  const int*   slen     = (const int*)d_in[2];
  const float* emb_tab  = (const float*)d_in[3];
  const float* Wsw      = (const float*)d_in[4];
  const float* Wsb      = (const float*)d_in[5];
  const float* Wzw      = (const float*)d_in[6];
  const float* Wzb      = (const float*)d_in[7];
  const float* Wrw      = (const float*)d_in[8];
  const float* Wrb      = (const float*)d_in[9];
  const float* Wnw      = (const float*)d_in[10];
  const float* Wnb      = (const float*)d_in[11];
  const float* Waw      = (const float*)d_in[12];
  const float* Wab      = (const float*)d_in[13];
  const float* vaw      = (const float*)d_in[14];
  const float* Wow      = (const float*)d_in[15];
  const float* Wob      = (const float*)d_in[16];

  char* ws = (char*)d_ws;
  size_t off = 0;
  auto alloc = [&](size_t bytes) -> void* {
    void* p = ws + off;
    off = (off + bytes + 255) & ~(size_t)255;
    return p;
  };
  us*    src_t  = (us*)alloc(SRC_ELEMS * 2);
  us*    ep_t   = (us*)alloc(SRC_ELEMS * 2);
  us*    emb_bf = (us*)alloc((size_t)NSTEPS * BATCH * NE * 2);
  us*    W1cat  = (us*)alloc((size_t)N1 * 1280 * 2);
  us*    Wns    = (us*)alloc((size_t)512 * 512 * 2);
  us*    Was    = (us*)alloc((size_t)512 * 512 * 2);
  us*    Wae    = (us*)alloc((size_t)512 * 512 * 2);
  us*    Wsbf   = (us*)alloc((size_t)512 * 512 * 2);
  float* bcat   = (float*)alloc((size_t)N1 * 4);
  float* s_f32  = (float*)alloc((size_t)BATCH * NH * 4);
  us*    s_bf   = (us*)alloc((size_t)BATCH * NH * 2);
  float* zi     = (float*)alloc((size_t)BATCH * NH * 4);
  float* npart  = (float*)alloc((size_t)BATCH * NH * 4);
  us*    xn_bf  = (us*)alloc((size_t)BATCH * NH * 2);
  us*    ci_bf  = (us*)alloc((size_t)BATCH * NH * 2);

  float* out         = (float*)d_out;
  float* dec_outputs = out;
  float* dec_states  = out + (size_t)NSTEPS * BATCH * NH;
  float* dec_attns   = dec_states + (size_t)NSTEPS * BATCH * NH;

  // ---- prologue ----
  k_conv_src<<<4096, 256, 0, stream>>>(src_enc, src_t);
  k_conv_w<<<2048, 256, 0, stream>>>(Wow, Wzw, Wrw, Wnw, Waw, Wsw,
                                     Wob, Wzb, Wrb, Wnb,
                                     W1cat, Wns, Was, Wae, Wsbf, bcat);
  k_emb<<<2048, 256, 0, stream>>>(tgt, emb_tab, emb_bf);
  // s0 = tanh(src_enc[0] @ Ws^T + Ws_b): src_t rows (b, s=0) at stride S*NH
  k_gemm<EPI_S0><<<dim3(4, 4), 512, 0, stream>>>(
      src_t, S_LEN * NH, Wsbf, 512, 512, Wsb, s_f32, s_bf);
  // ep_t[b,s] = src_t[b,s] @ Wae^T + Wa_b
  k_gemm<EPI_EPROJ><<<dim3(1024, 4), 512, 0, stream>>>(
      src_t, 512, Wae, 512, 512, Wab, nullptr, ep_t);

  // ---- 127 steps x 2 kernels ----
  for (int t = 0; t < NSTEPS; t++) {
    k_stepA<<<BATCH, 512, 0, stream>>>(
        ep_t, src_t, Wns, Was, vaw, slen, zi, npart, xn_bf,
        s_f32, s_bf, ci_bf,
        dec_states + (size_t)t * BATCH * NH,
        dec_attns + (size_t)t * BATCH * S_LEN, t > 0 ? 1 : 0);
    k_stepB<<<64, 256, 0, stream>>>(
        emb_bf + (size_t)t * BATCH * NE, s_bf, ci_bf, W1cat, bcat, s_f32,
        dec_outputs + (size_t)t * BATCH * NH, zi, npart, xn_bf);
  }
}

// Round 10
// 10674.700 us; speedup vs baseline: 1.4164x; 1.4164x over previous
//
#include <hip/hip_runtime.h>
#include <hip/hip_bf16.h>
#include <cstdint>
#include <cstddef>

namespace {

constexpr int S_LEN  = 256;
constexpr int BATCH  = 256;
constexpr int NH     = 512;
constexpr int NE     = 256;
constexpr int NSTEPS = 127;          // TGT_LEN-1
constexpr int N1     = 2048;         // [Wo;Wz;Wr;Wn_partial]
constexpr size_t SB        = (size_t)S_LEN * BATCH;   // 65536
constexpr size_t SRC_ELEMS = SB * NH;                 // 33,554,432
constexpr int RW = 1024;             // cat row width (elems): [ep 512 | src 512]

typedef __attribute__((ext_vector_type(8))) short  short8v;
typedef __attribute__((ext_vector_type(4))) float  float4v;
typedef unsigned short us;

constexpr int EPI_EPROJ = 1, EPI_S0 = 4;

__device__ __forceinline__ float bf2f(us u) {
  union { unsigned int i; float f; } c; c.i = ((unsigned int)u) << 16; return c.f;
}
__device__ __forceinline__ us f2bf(float f) {
  union { float f; unsigned int i; } c; c.f = f;
  unsigned int x = c.i;
  return (us)((x + 0x7FFFu + ((x >> 16) & 1u)) >> 16);
}
// tanh(x) = 1 - 2/(e^{2x}+1)
__device__ __forceinline__ float tanh2(float x) {
  return 1.f - 2.f * __builtin_amdgcn_rcpf(__expf(2.f * x) + 1.f);
}
__device__ __forceinline__ float sigm(float x) {
  return __builtin_amdgcn_rcpf(1.f + __expf(-x));
}

// ---------------- prologue: conversions ----------------

// src_enc (S,B,H) f32 -> cat src-half: cat[(b*S+s)*RW + 512 + h] bf16
__global__ void k_conv_src(const float* __restrict__ src, us* __restrict__ cat) {
  const int total = S_LEN * BATCH * 64;       // 8-elem chunks
  int i = blockIdx.x * blockDim.x + threadIdx.x;
  int stride = gridDim.x * blockDim.x;
  for (; i < total; i += stride) {
    int c = i & 63, s = (i >> 6) & 255, b = i >> 14;
    const float* p = src + ((size_t)s * BATCH + b) * NH + c * 8;
    float4 v0 = *(const float4*)p;
    float4 v1 = *(const float4*)(p + 4);
    us o[8] = { f2bf(v0.x), f2bf(v0.y), f2bf(v0.z), f2bf(v0.w),
                f2bf(v1.x), f2bf(v1.y), f2bf(v1.z), f2bf(v1.w) };
    *(short8v*)(cat + ((size_t)b * S_LEN + s) * RW + 512 + c * 8) =
        *(const short8v*)o;
  }
}

__global__ void k_conv_w(const float* __restrict__ Wo, const float* __restrict__ Wz,
                         const float* __restrict__ Wr, const float* __restrict__ Wn,
                         const float* __restrict__ Wa, const float* __restrict__ Ws,
                         const float* __restrict__ Wob, const float* __restrict__ Wzb,
                         const float* __restrict__ Wrb, const float* __restrict__ Wnb,
                         us* __restrict__ W1cat, us* __restrict__ Wns,
                         us* __restrict__ Was, us* __restrict__ Wae,
                         us* __restrict__ Wsbf, float* __restrict__ bcat) {
  const int T1 = 2048 * 1280;
  const int T2 = 512 * 512;
  const int total = T1 + 4 * T2 + 2048;
  int i = blockIdx.x * blockDim.x + threadIdx.x;
  int stride = gridDim.x * blockDim.x;
  for (; i < total; i += stride) {
    int idx = i;
    if (idx < T1) {
      int row = idx / 1280, col = idx - row * 1280;
      float v;
      if      (row < 512)  v = Wo[row * 1280 + col];
      else if (row < 1024) v = Wz[(row - 512) * 1280 + col];
      else if (row < 1536) v = Wr[(row - 1024) * 1280 + col];
      else {
        int g = row - 1536;
        v = (col >= 256 && col < 768) ? 0.f : Wn[g * 1280 + col];
      }
      W1cat[idx] = f2bf(v);
    } else if ((idx -= T1) < T2) {
      int g = idx >> 9, j = idx & 511;
      Wns[idx] = f2bf(Wn[g * 1280 + 256 + j]);
    } else if ((idx -= T2) < T2) {
      int g = idx >> 9, h = idx & 511;
      Was[idx] = f2bf(Wa[g * 1024 + h]);
    } else if ((idx -= T2) < T2) {
      int g = idx >> 9, h = idx & 511;
      Wae[idx] = f2bf(Wa[g * 1024 + 512 + h]);
    } else if ((idx -= T2) < T2) {
      Wsbf[idx] = f2bf(Ws[idx]);
    } else {
      idx -= T2;
      bcat[idx] = (idx < 512) ? Wob[idx]
                : (idx < 1024) ? Wzb[idx - 512]
                : (idx < 1536) ? Wrb[idx - 1024]
                               : Wnb[idx - 1536];
    }
  }
}

__global__ void k_emb(const int* __restrict__ tgt, const float* __restrict__ table,
                      us* __restrict__ emb) {
  const int total = NSTEPS * BATCH * NE;
  int i = blockIdx.x * blockDim.x + threadIdx.x;
  int stride = gridDim.x * blockDim.x;
  for (; i < total; i += stride) {
    int e  = i & (NE - 1);
    int tb = i >> 8;
    int sym = tgt[tb];
    emb[i] = f2bf(table[sym * NE + e]);
  }
}

// ------------- prologue 8-wave MFMA GEMM tile: 64x128, BK=64 (s0 / eproj) ----------
template<int EPI>
__global__ __launch_bounds__(512, 2) void k_gemm(
    const us* __restrict__ A0, int lda, const us* __restrict__ Bw, int ldb, int K,
    const float* __restrict__ bias, float* __restrict__ f0, us* __restrict__ g0,
    int ldc) {
  __shared__ alignas(16) char smem[49152];
  char* As0 = smem;               // 2 x 8192
  char* Bs0 = smem + 16384;       // 2 x 16384
  const int tid = threadIdx.x;
  const int m0 = blockIdx.x * 64, n0 = blockIdx.y * 128;
  const int arow = tid >> 3, ac = (tid & 7) * 8;
  const int brow = tid >> 2, bc = (tid & 3) * 16;
  short8v ar, br0, br1;

  auto loadT = [&](int k0) {
    ar = *(const short8v*)(A0 + (size_t)(m0 + arow) * lda + (k0 + ac));
    const us* q = Bw + (size_t)(n0 + brow) * ldb + (k0 + bc);
    br0 = *(const short8v*)q;
    br1 = *(const short8v*)(q + 8);
  };
  auto stage = [&](int buf) {
    *(short8v*)(As0 + buf * 8192 + arow * 128 + ((ac * 2) ^ ((arow & 7) << 4))) = ar;
    char* bb = Bs0 + buf * 16384 + brow * 128;
    const int sw = (brow & 7) << 4;
    *(short8v*)(bb + ((bc * 2) ^ sw)) = br0;
    *(short8v*)(bb + ((bc * 2 + 16) ^ sw)) = br1;
  };

  const int lane = tid & 63, wave = tid >> 6;
  const int wm = (wave >> 2) * 32, wn = (wave & 3) * 32;
  const int fr = lane & 15, kq = lane >> 4;
  const int ra0 = wm + fr, ra1 = ra0 + 16;
  const int rb0 = wn + fr, rb1 = rb0 + 16;
  float4v acc00 = {0,0,0,0}, acc01 = {0,0,0,0}, acc10 = {0,0,0,0}, acc11 = {0,0,0,0};

  loadT(0);
  stage(0);
  const int nit = K >> 6;
  for (int it = 0; it < nit; ++it) {
    __syncthreads();
    if (it + 1 < nit) loadT((it + 1) << 6);
    const char* ab = As0 + (it & 1) * 8192;
    const char* bb = Bs0 + (it & 1) * 16384;
    #pragma unroll
    for (int ks = 0; ks < 2; ++ks) {
      const int cb = ks * 64 + kq * 16;
      short8v a0 = *(const short8v*)(ab + ra0 * 128 + (cb ^ ((ra0 & 7) << 4)));
      short8v a1 = *(const short8v*)(ab + ra1 * 128 + (cb ^ ((ra1 & 7) << 4)));
      short8v b0 = *(const short8v*)(bb + rb0 * 128 + (cb ^ ((rb0 & 7) << 4)));
      short8v b1 = *(const short8v*)(bb + rb1 * 128 + (cb ^ ((rb1 & 7) << 4)));
      acc00 = __builtin_amdgcn_mfma_f32_16x16x32_bf16(a0, b0, acc00, 0, 0, 0);
      acc01 = __builtin_amdgcn_mfma_f32_16x16x32_bf16(a0, b1, acc01, 0, 0, 0);
      acc10 = __builtin_amdgcn_mfma_f32_16x16x32_bf16(a1, b0, acc10, 0, 0, 0);
      acc11 = __builtin_amdgcn_mfma_f32_16x16x32_bf16(a1, b1, acc11, 0, 0, 0);
    }
    if (it + 1 < nit) stage((it + 1) & 1);
  }

  #pragma unroll
  for (int am = 0; am < 2; ++am) {
    #pragma unroll
    for (int bn = 0; bn < 2; ++bn) {
      float4v a = am ? (bn ? acc11 : acc10) : (bn ? acc01 : acc00);
      #pragma unroll
      for (int r = 0; r < 4; ++r) {
        const int rowO = m0 + wm + am * 16 + kq * 4 + r;
        const int colO = n0 + wn + bn * 16 + fr;
        float v = a[r];
        if (EPI == EPI_S0) {
          float tv = tanh2(v + bias[colO]);
          f0[(size_t)rowO * 512 + colO] = tv;
          g0[(size_t)rowO * ldc + colO] = f2bf(tv);
        } else { // EPI_EPROJ
          g0[(size_t)rowO * ldc + colO] = f2bf(v + bias[colO]);
        }
      }
    }
  }
}

// ---- k_stepA: GRU-finish + q (thread-per-row, R7-proven) + one-pass score/ci ----
__global__ __launch_bounds__(512, 4) void k_stepA(
    const us* __restrict__ cat,       // (B,S,RW) bf16: [ep|src]
    const us* __restrict__ Wns, const us* __restrict__ Was,
    const float* __restrict__ vaw, const int* __restrict__ slen,
    const float* __restrict__ zi, const float* __restrict__ npart,
    const us* __restrict__ xn,
    float* __restrict__ s_f32, us* __restrict__ s_bf, us* __restrict__ ci_bf,
    float* __restrict__ dec_st_t, float* __restrict__ dec_at_t, int has_gru) {
  __shared__ float sfl[512];
  __shared__ float q2l[512];
  __shared__ float pl[256];
  __shared__ float lred[8];
  __shared__ float wpart[8][512];              // 16KB; [0] doubles as xnf
  const int b = blockIdx.x, tid = threadIdx.x;
  const int lane = tid & 63, wv = tid >> 6;    // 8 waves
  const int g0l = lane * 8;
  const int len = slen[b];

  // hoisted attention constants
  float vv2[8]; float sumv = 0.f;
  {
    const float* vp = vaw + g0l;
    #pragma unroll
    for (int j = 0; j < 8; j++) { vv2[j] = 2.f * vp[j]; sumv += vp[j]; }
    #pragma unroll
    for (int off = 32; off > 0; off >>= 1) sumv += __shfl_xor(sumv, off, 64);
  }

  // ---- M1: GRU finish of step t-1 -> s_t (thread-per-row matvec vs Wns) ----
  float s_new;
  if (has_gru) {
    float* xnf = &wpart[0][0];
    xnf[tid] = bf2f(xn[b * 512 + tid]);
    __syncthreads();
    const us* wr = Wns + (size_t)tid * 512;
    float acc = 0.f;
    #pragma unroll 8
    for (int k = 0; k < 64; ++k) {
      short8v w8 = ((const short8v*)wr)[k];
      #pragma unroll
      for (int j = 0; j < 8; j++)
        acc = __builtin_fmaf(bf2f((us)w8[j]), xnf[k * 8 + j], acc);
    }
    float z  = zi[b * 512 + tid];
    float so = s_f32[b * 512 + tid];
    float nv = tanh2(npart[b * 512 + tid] + acc);
    s_new = (1.f - z) * so + z * nv;
    s_f32[b * 512 + tid] = s_new;
    s_bf[b * 512 + tid]  = f2bf(s_new);
    __syncthreads();          // xnf (wpart[0]) free again
  } else {
    s_new = s_f32[b * 512 + tid];
  }
  sfl[tid] = s_new;
  __builtin_nontemporal_store(s_new, &dec_st_t[b * 512 + tid]);
  __syncthreads();

  // ---- M2: q = 2 * (s_t @ Was^T) (thread-per-row matvec) ----
  {
    const us* wr = Was + (size_t)tid * 512;
    float acc = 0.f;
    #pragma unroll 8
    for (int k = 0; k < 64; ++k) {
      short8v w8 = ((const short8v*)wr)[k];
      #pragma unroll
      for (int j = 0; j < 8; j++)
        acc = __builtin_fmaf(bf2f((us)w8[j]), sfl[k * 8 + j], acc);
    }
    q2l[tid] = 2.f * acc;
  }
  __syncthreads();

  // ---- single-pass scores + ci (max-free softmax; reg pipeline 4 rows deep) ----
  float q2[8];
  #pragma unroll
  for (int j = 0; j < 8; j++) q2[j] = q2l[g0l + j];

  const us* cb = cat + (size_t)b * S_LEN * RW + g0l;   // +i*8*RW rows for wave wv
  float lsum = 0.f;
  float c8a = 0.f, c8b = 0.f, c8c = 0.f, c8d = 0.f,
        c8e = 0.f, c8f = 0.f, c8g = 0.f, c8h = 0.f;

  short8v e0, f0, e1, f1, e2, f2, e3, f3;
  auto LDR = [&](int i, short8v& ev, short8v& fv) {
    const us* p = cb + (size_t)(wv + 8 * i) * RW;
    ev = *(const short8v*)p;
    fv = *(const short8v*)(p + 512);
  };
  auto PROC = [&](int i, short8v& ev, short8v& fv) {
    const int s = wv + 8 * i;
    float acc = 0.f;
    #pragma unroll
    for (int j = 0; j < 8; j++) {
      float arg = __builtin_fmaf(bf2f((us)ev[j]), 2.f, q2[j]);
      acc = __builtin_fmaf(vv2[j], __builtin_amdgcn_rcpf(__expf(arg) + 1.f), acc);
    }
    #pragma unroll
    for (int off = 32; off > 0; off >>= 1) acc += __shfl_xor(acc, off, 64);
    float p = (s < len) ? __expf(sumv - acc) : 0.f;
    if (lane == 0) pl[s] = p;
    lsum += p;
    c8a = __builtin_fmaf(p, bf2f((us)fv[0]), c8a);
    c8b = __builtin_fmaf(p, bf2f((us)fv[1]), c8b);
    c8c = __builtin_fmaf(p, bf2f((us)fv[2]), c8c);
    c8d = __builtin_fmaf(p, bf2f((us)fv[3]), c8d);
    c8e = __builtin_fmaf(p, bf2f((us)fv[4]), c8e);
    c8f = __builtin_fmaf(p, bf2f((us)fv[5]), c8f);
    c8g = __builtin_fmaf(p, bf2f((us)fv[6]), c8g);
    c8h = __builtin_fmaf(p, bf2f((us)fv[7]), c8h);
  };

  LDR(0, e0, f0); LDR(1, e1, f1); LDR(2, e2, f2); LDR(3, e3, f3);
  for (int i = 0; i < 32; i += 4) {
    PROC(i + 0, e0, f0); if (i + 4 < 32) LDR(i + 4, e0, f0);
    PROC(i + 1, e1, f1); if (i + 5 < 32) LDR(i + 5, e1, f1);
    PROC(i + 2, e2, f2); if (i + 6 < 32) LDR(i + 6, e2, f2);
    PROC(i + 3, e3, f3); if (i + 7 < 32) LDR(i + 7, e3, f3);
  }

  if (lane == 0) lred[wv] = lsum;
  {
    float w0_[8] = { c8a, c8b, c8c, c8d, c8e, c8f, c8g, c8h };
    #pragma unroll
    for (int j = 0; j < 8; j++) wpart[wv][g0l + j] = w0_[j];
  }
  __syncthreads();
  float l = 0.f;
  #pragma unroll
  for (int w = 0; w < 8; w++) l += lred[w];
  const float inv = __builtin_amdgcn_rcpf(l);

  if (tid < 256)
    __builtin_nontemporal_store(pl[tid] * inv, &dec_at_t[b * 256 + tid]);

  float cv = 0.f;
  #pragma unroll
  for (int w = 0; w < 8; w++) cv += wpart[w][tid];
  ci_bf[b * 512 + tid] = f2bf(cv * inv);
}

// -------- k_stepB: Y = [emb|s|ci] @ W1cat^T + bcat --------
__global__ __launch_bounds__(256, 4) void k_stepB(
    const us* __restrict__ emb_t, const us* __restrict__ sbf,
    const us* __restrict__ cibf, const us* __restrict__ W1cat,
    const float* __restrict__ bcat, const float* __restrict__ s_f32,
    float* __restrict__ dec_out_t, float* __restrict__ zi,
    float* __restrict__ npart, us* __restrict__ xn) {
  __shared__ alignas(16) char smem[24576];
  const int bid = blockIdx.x, tid = threadIdx.x;
  const int lane = tid & 63, wv = tid >> 6;
  char* As = smem;            // 64 x 128B
  char* Bs = smem + 8192;     // 128 x 128B
  const int m0 = (bid >> 4) * 64, n0 = (bid & 15) * 128;
  const int fr = lane & 15, kq = lane >> 4;
  const int wm = (wv & 1) * 32, wn0 = (wv >> 1) * 32;
  const int ra0 = wm + fr, ra1 = ra0 + 16;
  float4v acc[2][2][2];
  #pragma unroll
  for (int x = 0; x < 2; x++)
    #pragma unroll
    for (int y = 0; y < 2; y++)
      #pragma unroll
      for (int z = 0; z < 2; z++) acc[x][y][z] = (float4v){0,0,0,0};

  for (int kt = 0; kt < 20; ++kt) {
    __syncthreads();
    #pragma unroll
    for (int j = 0; j < 2; j++) {
      int cid = tid + 256 * j;
      int arow = cid >> 3, ac8 = (cid & 7) * 8;
      int cc = kt * 64 + ac8, rowg = m0 + arow;
      const us* p = (cc < 256) ? emb_t + (size_t)rowg * 256 + cc
                  : (cc < 768) ? sbf + (size_t)rowg * 512 + (cc - 256)
                               : cibf + (size_t)rowg * 512 + (cc - 768);
      *(short8v*)(As + arow * 128 + ((ac8 * 2) ^ ((arow & 7) << 4))) =
          *(const short8v*)p;
    }
    #pragma unroll
    for (int j = 0; j < 4; j++) {
      int cid = tid + 256 * j;
      int brow = cid >> 3, bc8 = (cid & 7) * 8;
      *(short8v*)(Bs + brow * 128 + ((bc8 * 2) ^ ((brow & 7) << 4))) =
          *(const short8v*)(W1cat + (size_t)(n0 + brow) * 1280 + kt * 64 + bc8);
    }
    __syncthreads();
    #pragma unroll
    for (int ks = 0; ks < 2; ++ks) {
      const int cb = ks * 64 + kq * 16;
      short8v a0 = *(const short8v*)(As + ra0 * 128 + (cb ^ ((ra0 & 7) << 4)));
      short8v a1 = *(const short8v*)(As + ra1 * 128 + (cb ^ ((ra1 & 7) << 4)));
      #pragma unroll
      for (int nh = 0; nh < 2; ++nh) {
        const int rb0 = wn0 + nh * 64 + fr, rb1 = rb0 + 16;
        short8v b0 = *(const short8v*)(Bs + rb0 * 128 + (cb ^ ((rb0 & 7) << 4)));
        short8v b1 = *(const short8v*)(Bs + rb1 * 128 + (cb ^ ((rb1 & 7) << 4)));
        acc[nh][0][0] = __builtin_amdgcn_mfma_f32_16x16x32_bf16(a0, b0, acc[nh][0][0], 0, 0, 0);
        acc[nh][0][1] = __builtin_amdgcn_mfma_f32_16x16x32_bf16(a0, b1, acc[nh][0][1], 0, 0, 0);
        acc[nh][1][0] = __builtin_amdgcn_mfma_f32_16x16x32_bf16(a1, b0, acc[nh][1][0], 0, 0, 0);
        acc[nh][1][1] = __builtin_amdgcn_mfma_f32_16x16x32_bf16(a1, b1, acc[nh][1][1], 0, 0, 0);
      }
    }
  }

  #pragma unroll
  for (int nh = 0; nh < 2; ++nh) {
    #pragma unroll
    for (int am = 0; am < 2; ++am) {
      #pragma unroll
      for (int bn = 0; bn < 2; ++bn) {
        #pragma unroll
        for (int r = 0; r < 4; ++r) {
          const int rowO = m0 + wm + am * 16 + kq * 4 + r;
          const int colO = n0 + wn0 + nh * 64 + bn * 16 + fr;
          float v = acc[nh][am][bn][r] + bcat[colO];
          const int qd = colO >> 9, j = colO & 511;
          const size_t idx = (size_t)rowO * 512 + j;
          if      (qd == 0) __builtin_nontemporal_store(v, &dec_out_t[idx]);
          else if (qd == 1) zi[idx] = sigm(v);
          else if (qd == 2) xn[idx] = f2bf(sigm(v) * s_f32[idx]);
          else              npart[idx] = v;
        }
      }
    }
  }
}

} // namespace

extern "C" void kernel_launch(void* const* d_in, const int* in_sizes, int n_in,
                              void* d_out, int out_size, void* d_ws, size_t ws_size,
                              hipStream_t stream) {
  const float* src_enc  = (const float*)d_in[0];
  const int*   tgt      = (const int*)d_in[1];
  const int*   slen     = (const int*)d_in[2];
  const float* emb_tab  = (const float*)d_in[3];
  const float* Wsw      = (const float*)d_in[4];
  const float* Wsb      = (const float*)d_in[5];
  const float* Wzw      = (const float*)d_in[6];
  const float* Wzb      = (const float*)d_in[7];
  const float* Wrw      = (const float*)d_in[8];
  const float* Wrb      = (const float*)d_in[9];
  const float* Wnw      = (const float*)d_in[10];
  const float* Wnb      = (const float*)d_in[11];
  const float* Waw      = (const float*)d_in[12];
  const float* Wab      = (const float*)d_in[13];
  const float* vaw      = (const float*)d_in[14];
  const float* Wow      = (const float*)d_in[15];
  const float* Wob      = (const float*)d_in[16];

  char* ws = (char*)d_ws;
  size_t off = 0;
  auto alloc = [&](size_t bytes) -> void* {
    void* p = ws + off;
    off = (off + bytes + 255) & ~(size_t)255;
    return p;
  };
  us*    cat    = (us*)alloc(SB * RW * 2);             // 128 MB interleaved [ep|src]
  us*    emb_bf = (us*)alloc((size_t)NSTEPS * BATCH * NE * 2);
  us*    W1cat  = (us*)alloc((size_t)N1 * 1280 * 2);
  us*    Wns    = (us*)alloc((size_t)512 * 512 * 2);
  us*    Was    = (us*)alloc((size_t)512 * 512 * 2);
  us*    Wae    = (us*)alloc((size_t)512 * 512 * 2);
  us*    Wsbf   = (us*)alloc((size_t)512 * 512 * 2);
  float* bcat   = (float*)alloc((size_t)N1 * 4);
  float* s_f32  = (float*)alloc((size_t)BATCH * NH * 4);
  us*    s_bf   = (us*)alloc((size_t)BATCH * NH * 2);
  float* zi     = (float*)alloc((size_t)BATCH * NH * 4);
  float* npart  = (float*)alloc((size_t)BATCH * NH * 4);
  us*    xn_bf  = (us*)alloc((size_t)BATCH * NH * 2);
  us*    ci_bf  = (us*)alloc((size_t)BATCH * NH * 2);

  float* out         = (float*)d_out;
  float* dec_outputs = out;
  float* dec_states  = out + (size_t)NSTEPS * BATCH * NH;
  float* dec_attns   = dec_states + (size_t)NSTEPS * BATCH * NH;

  // ---- prologue ----
  k_conv_src<<<4096, 256, 0, stream>>>(src_enc, cat);
  k_conv_w<<<2048, 256, 0, stream>>>(Wow, Wzw, Wrw, Wnw, Waw, Wsw,
                                     Wob, Wzb, Wrb, Wnb,
                                     W1cat, Wns, Was, Wae, Wsbf, bcat);
  k_emb<<<2048, 256, 0, stream>>>(tgt, emb_tab, emb_bf);
  // s0 = tanh(src_enc[0] @ Ws^T + Ws_b): A = cat src-half rows (b, s=0)
  k_gemm<EPI_S0><<<dim3(4, 4), 512, 0, stream>>>(
      cat + 512, S_LEN * RW, Wsbf, 512, 512, Wsb, s_f32, s_bf, 512);
  // ep half: cat[.,.,0..511] = srcrow @ Wae^T + Wa_b
  k_gemm<EPI_EPROJ><<<dim3(1024, 4), 512, 0, stream>>>(
      cat + 512, RW, Wae, 512, 512, Wab, nullptr, cat, RW);

  // ---- 127 steps x 2 kernels ----
  for (int t = 0; t < NSTEPS; t++) {
    k_stepA<<<BATCH, 512, 0, stream>>>(
        cat, Wns, Was, vaw, slen, zi, npart, xn_bf,
        s_f32, s_bf, ci_bf,
        dec_states + (size_t)t * BATCH * NH,
        dec_attns + (size_t)t * BATCH * S_LEN, t > 0 ? 1 : 0);
    k_stepB<<<64, 256, 0, stream>>>(
        emb_bf + (size_t)t * BATCH * NE, s_bf, ci_bf, W1cat, bcat, s_f32,
        dec_outputs + (size_t)t * BATCH * NH, zi, npart, xn_bf);
  }
}